// Round 13
// baseline (1659.434 us; speedup 1.0000x reference)
//
#include <hip/hip_runtime.h>
#include <hip/hip_bf16.h>

#define N_NODES    100000
#define N_EDGES    1600000
#define IN_CH      128
#define HID        64
#define N_LAYERS   4
#define OUT_CH     10
#define NUM_GRAPHS 128
#define BN_EPS     1e-5f
#define CAP        64             // padded CSR row capacity (max deg ~36 at Poisson(16))
#define NREP       8              // pooled replicas (cuts per-address atomic chains 8x)
#define NBKT       256            // dst>>9 -> buckets 0..195 (256 slots for pow2 LDS)
#define EPB        2048           // edges per block in partition kernels
#define PNB        782            // ceil(1.6M / 2048)
#define PADM       24             // row pad multiple: 12 dual-loads per batch

typedef __hip_bfloat16 bf16;
typedef unsigned int uint32;

__device__ __forceinline__ float bf2f(bf16 v) { return __bfloat162float(v); }
// unpack packed bf16x2 dword -> float2 (bf16 -> f32 is <<16)
__device__ __forceinline__ float2 unpk(uint32 p) {
    float2 r;
    r.x = __uint_as_float(p << 16);
    r.y = __uint_as_float(p & 0xffff0000u);
    return r;
}

// ---------------- tiny zero (ghist only; cnt/pooled zeroed inside bhist) -----
__global__ void zero_i(int* __restrict__ p, int n) {
    int i = threadIdx.x;
    for (; i < n; i += 256) p[i] = 0;
}

// ---------------- bucket histogram (LDS-aggregated) + bulk zeroing -----------
__global__ void bhist(const int* __restrict__ dst, int* __restrict__ ghist,
                      int* __restrict__ zbase, int zn) {
    __shared__ int h[NBKT];
    int t = threadIdx.x;
    h[t] = 0;
    // fused zeroing of cnt+pooled (disjoint from this kernel's own arrays)
    for (int i = blockIdx.x * 256 + t; i < zn; i += gridDim.x * 256) zbase[i] = 0;
    __syncthreads();
    long base = (long)blockIdx.x * EPB;
    for (int u = 0; u < 8; u++) {
        long e = base + u * 256 + t;
        if (e < N_EDGES) atomicAdd(&h[dst[e] >> 9], 1);
    }
    __syncthreads();
    if (h[t]) atomicAdd(&ghist[t], h[t]);
}

// ---------------- bucket scan + cntg (binary search) + ybf pad-row zero ------
__global__ void bscan(const int* __restrict__ ghist, int* __restrict__ gcursor,
                      const int* __restrict__ batch, int* __restrict__ cntg,
                      bf16* __restrict__ ybfA, bf16* __restrict__ ybfB) {
    __shared__ int sh[NBKT];
    int t = threadIdx.x;                          // 256 threads
    int v = ghist[t];
    sh[t] = v;
    __syncthreads();
    for (int off = 1; off < NBKT; off <<= 1) {
        int a = (t >= off) ? sh[t - off] : 0;
        __syncthreads();
        sh[t] += a;
        __syncthreads();
    }
    gcursor[t] = sh[t] - v;                       // exclusive bucket base
    if (t < NUM_GRAPHS) {                         // per-graph node counts
        int g = t, lo = 0, hi = N_NODES;
        while (lo < hi) { int m = (lo + hi) >> 1; if (batch[m] < g) lo = m + 1; else hi = m; }
        int lb = lo;
        lo = 0; hi = N_NODES;
        while (lo < hi) { int m = (lo + hi) >> 1; if (batch[m] < g + 1) lo = m + 1; else hi = m; }
        cntg[g] = lo - lb;
    }
    if (t < HID) {                                // sentinel zero-row for tail-free gather
        ybfA[(long)N_NODES * HID + t] = __float2bfloat16(0.f);
        ybfB[(long)N_NODES * HID + t] = __float2bfloat16(0.f);
    }
}

// ---------------- partition edges into bucket order --------------------------
__global__ void bpart(const int* __restrict__ src, const int* __restrict__ dst,
                      int* __restrict__ gcursor, int2* __restrict__ epart) {
    __shared__ int h[NBKT];
    __shared__ int cur[NBKT];
    int t = threadIdx.x;
    h[t] = 0;
    __syncthreads();
    long base = (long)blockIdx.x * EPB;
    int myd[8], mys[8];
    for (int u = 0; u < 8; u++) {
        long e = base + u * 256 + t;
        if (e < N_EDGES) {
            myd[u] = dst[e];
            mys[u] = src[e];
            atomicAdd(&h[myd[u] >> 9], 1);
        } else myd[u] = -1;
    }
    __syncthreads();
    if (h[t]) cur[t] = atomicAdd(&gcursor[t], h[t]);
    __syncthreads();
    for (int u = 0; u < 8; u++) {
        if (myd[u] >= 0) {
            int pos = atomicAdd(&cur[myd[u] >> 9], 1);
            epart[pos] = make_int2(mys[u], myd[u]);
        }
    }
}

// ---------------- fill padded CSR from bucket-sorted edges -------------------
__global__ void fillp(const int2* __restrict__ epart, int* __restrict__ cnt,
                      int* __restrict__ col) {
    int t = threadIdx.x;
    long base = (long)blockIdx.x * EPB;
    for (int u = 0; u < 8; u++) {
        long e = base + u * 256 + t;
        if (e < N_EDGES) {
            int2 p = epart[e];
            int slot = atomicAdd(&cnt[p.y], 1);
            col[p.y * CAP + slot] = p.x;
        }
    }
}

// ---------------- pad each row to a multiple of PADM with sentinel -----------
__global__ void pad_rows(const int* __restrict__ cnt, int* __restrict__ col) {
    int n = blockIdx.x * 256 + threadIdx.x;       // 391 blocks
    if (n >= N_NODES) return;
    int c = cnt[n];
    int cp = ((c + PADM - 1) / PADM) * PADM;      // <= 48 for max deg ~36
    for (int s = c; s < cp; s++) col[n * CAP + s] = N_NODES;
}

// ---------------- weight transposes (for float4 per-lane weight loads) -------
// b=0: W1f(128x64)->W1fT(64x128); b=1..4: W2 of layer b-1 -> WT2; b=5..7: W1r[b-5] -> WTn
__global__ void wtrans(const float* __restrict__ W1f, const float* __restrict__ W2f,
                       const float* __restrict__ W1r, const float* __restrict__ W2r,
                       float* __restrict__ W1fT, float* __restrict__ WT2,
                       float* __restrict__ WTn) {
    int b = blockIdx.x, t = threadIdx.x;
    if (b == 0) {
        for (int i = t; i < IN_CH * 64; i += 256) {
            int r = i >> 6, c = i & 63;
            W1fT[c * IN_CH + r] = W1f[i];
        }
    } else if (b <= 4) {
        const float* W = (b == 1) ? W2f : (W2r + (long)(b - 2) * 4096);
        float* D = WT2 + (long)(b - 1) * 4096;
        for (int i = t; i < 4096; i += 256) {
            int r = i >> 6, c = i & 63;
            D[c * 64 + r] = W[i];
        }
    } else {
        const float* W = W1r + (long)(b - 5) * 4096;
        float* D = WTn + (long)(b - 5) * 4096;
        for (int i = t; i < 4096; i += 256) {
            int r = i >> 6, c = i & 63;
            D[c * 64 + r] = W[i];
        }
    }
}

// ---------------- layer-0 pre-projection: ybf = bf16(x @ W1f) (no bias) ------
// 4 nodes per wave; transposed W1fT -> float4 weight loads.
__global__ void proj0(const float* __restrict__ x, const float* __restrict__ W1fT,
                      bf16* __restrict__ ybf) {
    __shared__ float xsh[4][4][IN_CH];            // 8 KB
    const int wave = threadIdx.x >> 6, lane = threadIdx.x & 63;
    const int nb = blockIdx.x * 16 + wave * 4;    // 6250 * 16 == 100000
    #pragma unroll
    for (int r = 0; r < 4; r++) {
        float2 v = ((const float2*)(x + (long)(nb + r) * IN_CH))[lane];
        xsh[wave][r][2 * lane]     = v.x;         // 2-way bank alias: free
        xsh[wave][r][2 * lane + 1] = v.y;
    }
    // per-wave LDS slice: wave-lockstep + compiler lgkmcnt; no barrier
    const float* wrow = W1fT + lane * IN_CH;
    float a0 = 0.f, a1 = 0.f, a2 = 0.f, a3 = 0.f;
    for (int k = 0; k < IN_CH; k += 4) {
        float4 w = *(const float4*)&wrow[k];
        float4 q0 = *(const float4*)&xsh[wave][0][k];
        float4 q1 = *(const float4*)&xsh[wave][1][k];
        float4 q2 = *(const float4*)&xsh[wave][2][k];
        float4 q3 = *(const float4*)&xsh[wave][3][k];
        a0 += q0.x * w.x + q0.y * w.y + q0.z * w.z + q0.w * w.w;
        a1 += q1.x * w.x + q1.y * w.y + q1.z * w.z + q1.w * w.w;
        a2 += q2.x * w.x + q2.y * w.y + q2.z * w.z + q2.w * w.w;
        a3 += q3.x * w.x + q3.y * w.y + q3.z * w.z + q3.w * w.w;
    }
    ybf[(long)(nb + 0) * 64 + lane] = __float2bfloat16(a0);
    ybf[(long)(nb + 1) * 64 + lane] = __float2bfloat16(a1);
    ybf[(long)(nb + 2) * 64 + lane] = __float2bfloat16(a2);
    ybf[(long)(nb + 3) * 64 + lane] = __float2bfloat16(a3);
}

// ---------------- fused layer: dual-row gather -> relu -> W2 -> pool (+W1n) --
// 12-deep dual batches (24 slots); transposed weights -> float4 loads.
template <bool HAS_NEXT>
__global__ void layer_fused(const bf16* __restrict__ ybf, const int* __restrict__ cnt,
                            const int* __restrict__ col, const int* __restrict__ batch,
                            const float* __restrict__ b1, const float* __restrict__ W2T,
                            const float* __restrict__ b2, const float* __restrict__ W1nT,
                            bf16* __restrict__ ynext, float* __restrict__ pooled_l) {
    __shared__ float csh[4][2][2 * HID];          // half-sums, 4 KB
    __shared__ float tsh[4][64];
    __shared__ float hsh[4][64];
    const int wave = threadIdx.x >> 6, lane = threadIdx.x & 63;
    const int hl = lane & 31;
    const bool hi = lane >= 32;
    const int nA = blockIdx.x * 4;
    const int n = __builtin_amdgcn_readfirstlane(nA + wave);
    const int degc = __builtin_amdgcn_readfirstlane(cnt[n]);
    const int degp = ((degc + PADM - 1) / PADM) * PADM;
    const int g = __builtin_amdgcn_readfirstlane(batch[n]);
    const long s = (long)n * CAP;
    const uint32* yrow = (const uint32*)ybf;

    float2 a0 = {0.f, 0.f}, a1 = {0.f, 0.f}, a2 = {0.f, 0.f}, a3 = {0.f, 0.f};
    for (int i = 0; i < degp; i += PADM) {
        uint32 p[12];
        #pragma unroll
        for (int u = 0; u < 12; u++) {
            int c0 = __builtin_amdgcn_readfirstlane(col[s + i + 2 * u]);
            int c1 = __builtin_amdgcn_readfirstlane(col[s + i + 2 * u + 1]);
            int c = hi ? c1 : c0;
            p[u] = yrow[(long)c * 32 + hl];
        }
        #pragma unroll
        for (int u = 0; u < 12; u++) {
            float2 f = unpk(p[u]);
            if ((u & 3) == 0) { a0.x += f.x; a0.y += f.y; }
            else if ((u & 3) == 1) { a1.x += f.x; a1.y += f.y; }
            else if ((u & 3) == 2) { a2.x += f.x; a2.y += f.y; }
            else { a3.x += f.x; a3.y += f.y; }
        }
    }
    float2 hs;
    hs.x = (a0.x + a1.x) + (a2.x + a3.x);
    hs.y = (a0.y + a1.y) + (a2.y + a3.y);
    ((float2*)&csh[wave][hi ? 1 : 0][0])[hl] = hs;   // channels (2hl, 2hl+1)
    // per-wave slice: lockstep + compiler lgkmcnt; no barrier
    float t = bf2f(ybf[(long)n * 64 + lane]) + b1[lane]
            + csh[wave][0][lane] + csh[wave][1][lane];
    t = fmaxf(t, 0.f);
    tsh[wave][lane] = t;

    const float* w2row = W2T + lane * 64;
    float h = b2[lane];
    for (int k = 0; k < 64; k += 4) {
        float4 tv = *(const float4*)&tsh[wave][k];
        float4 wv = *(const float4*)&w2row[k];
        h += tv.x * wv.x + tv.y * wv.y + tv.z * wv.z + tv.w * wv.w;
    }
    h = fmaxf(h, 0.f);
    hsh[wave][lane] = h;

    if (HAS_NEXT) {               // reads only own wave's hsh slice: pre-barrier OK
        const float* wnrow = W1nT + lane * 64;
        float yn = 0.f;
        for (int k = 0; k < 64; k += 4) {
            float4 hv = *(const float4*)&hsh[wave][k];
            float4 wv = *(const float4*)&wnrow[k];
            yn += hv.x * wv.x + hv.y * wv.y + hv.z * wv.z + hv.w * wv.w;
        }
        ynext[(long)n * 64 + lane] = __float2bfloat16(yn);
    }

    // block-aggregated pool contribution (replicated target cuts chains 8x)
    __syncthreads();
    float* rep = pooled_l + (long)(blockIdx.x & (NREP - 1)) * NUM_GRAPHS * HID;
    const int gA = __builtin_amdgcn_readfirstlane(batch[nA]);
    const int gD = __builtin_amdgcn_readfirstlane(batch[nA + 3]);
    if (gA == gD) {               // 99.5% of blocks: whole block same graph
        if (wave == 0) {
            float sum = (hsh[0][lane] + hsh[1][lane]) + (hsh[2][lane] + hsh[3][lane]);
            atomicAdd(&rep[gA * 64 + lane], sum);
        }
    } else {
        atomicAdd(&rep[g * 64 + lane], h);
    }
}

// ---------------- JK projection on pooled sums (exact: pooling is linear) ----
__global__ void jk_pool(const float* __restrict__ pooled, const int* __restrict__ cntg,
                        const float* __restrict__ Wjk, const float* __restrict__ bjk,
                        float* __restrict__ pooled_jk) {
    __shared__ float sh[64];
    int g = blockIdx.x, j = threadIdx.x;          // 128 blocks x 64 threads (1 wave)
    float acc = (float)cntg[g] * bjk[j];
    for (int l = 0; l < N_LAYERS; l++) {
        float s = 0.f;
        for (int r = 0; r < NREP; r++)
            s += pooled[((long)(l * NREP + r) * NUM_GRAPHS + g) * 64 + j];
        sh[j] = s;                                // single wave: lockstep, no barrier
        const float* W = Wjk + (long)l * HID * 64;
        for (int k = 0; k < 64; k++) acc += sh[k] * W[k * 64 + j];
    }
    pooled_jk[g * 64 + j] = acc;
}

// ---------------- classifier: Linear -> BN(batch stats) -> ReLU -> Linear ----
__global__ void cls_all(const float* __restrict__ pooled_jk,
                        const float* __restrict__ Wc1, const float* __restrict__ bc1,
                        const float* __restrict__ gamma, const float* __restrict__ beta,
                        const float* __restrict__ Wc2, const float* __restrict__ bc2,
                        float* __restrict__ out) {
    __shared__ float Z[NUM_GRAPHS * HID];         // 32 KB
    __shared__ float mu[HID], rs[HID];
    int tid = threadIdx.x;                        // 256

    for (int i = tid; i < NUM_GRAPHS * HID; i += 256) {
        int g = i >> 6, j = i & 63;
        float acc = bc1[j];
        for (int k = 0; k < 64; k++) acc += pooled_jk[g * 64 + k] * Wc1[k * 64 + j];
        Z[i] = acc;
    }
    __syncthreads();
    if (tid < HID) {
        float s = 0.f, sq = 0.f;
        for (int g = 0; g < NUM_GRAPHS; g++) {
            float v = Z[g * 64 + tid];
            s += v; sq += v * v;
        }
        float m = s / NUM_GRAPHS;
        mu[tid] = m;
        rs[tid] = rsqrtf(sq / NUM_GRAPHS - m * m + BN_EPS);
    }
    __syncthreads();
    for (int i = tid; i < NUM_GRAPHS * OUT_CH; i += 256) {
        int g = i / OUT_CH, o = i % OUT_CH;
        float acc = bc2[o];
        for (int j = 0; j < 64; j++) {
            float v = (Z[g * 64 + j] - mu[j]) * rs[j] * gamma[j] + beta[j];
            acc += fmaxf(v, 0.f) * Wc2[j * OUT_CH + o];
        }
        out[i] = acc;
    }
}

// -----------------------------------------------------------------------------
extern "C" void kernel_launch(void* const* d_in, const int* in_sizes, int n_in,
                              void* d_out, int out_size, void* d_ws, size_t ws_size,
                              hipStream_t stream) {
    const float* x     = (const float*)d_in[0];
    const int*   ei    = (const int*)d_in[1];
    const int*   batch = (const int*)d_in[2];
    const float* W1f   = (const float*)d_in[3];
    const float* b1f   = (const float*)d_in[4];
    const float* W2f   = (const float*)d_in[5];
    const float* b2f   = (const float*)d_in[6];
    const float* W1r   = (const float*)d_in[7];
    const float* b1r   = (const float*)d_in[8];
    const float* W2r   = (const float*)d_in[9];
    const float* b2r   = (const float*)d_in[10];
    const float* Wjk   = (const float*)d_in[11];
    const float* bjk   = (const float*)d_in[12];
    const float* Wc1   = (const float*)d_in[13];
    const float* bc1   = (const float*)d_in[14];
    const float* gamma = (const float*)d_in[15];
    const float* beta  = (const float*)d_in[16];
    const float* Wc2   = (const float*)d_in[17];
    const float* bc2   = (const float*)d_in[18];

    const int* src = ei;
    const int* dst = ei + N_EDGES;

    // workspace layout (all segments 16-B aligned)
    float* ws        = (float*)d_ws;
    float* pooled_jk = ws;                                      // 8192 floats
    bf16*  ybfA      = (bf16*)(pooled_jk + NUM_GRAPHS * HID);   // (N+1)*64 bf16
    bf16*  ybfB      = ybfA + (long)(N_NODES + 1) * HID;        // (N+1)*64 bf16
    int*   cnt       = (int*)(ybfB + (long)(N_NODES + 1) * HID);// 100000
    float* pooled    = (float*)(cnt + N_NODES);                 // 262144 floats
    int*   ghist     = (int*)(pooled + (long)N_LAYERS * NREP * NUM_GRAPHS * HID); // 256
    int*   gcursor   = ghist + NBKT;                            // 256
    int*   cntg      = gcursor + NBKT;                          // 128 (+pad 128)
    float* W1fT      = (float*)(cntg + 256);                    // 8192 floats
    float* WT2       = W1fT + IN_CH * 64;                       // 16384 floats
    float* WTn       = WT2 + 4 * 4096;                          // 12288 floats
    int*   col       = (int*)(WTn + 3 * 4096);                  // 6.4M ints
    int2*  epart     = (int2*)(col + (long)N_NODES * CAP);      // 1.6M int2
    const int ZN = N_NODES + N_LAYERS * NREP * NUM_GRAPHS * HID; // cnt + pooled

    // ---- CSR build: zero(ghist) -> hist(+bulk zero) -> scan -> part -> fill --
    zero_i<<<1, 256, 0, stream>>>(ghist, NBKT);
    bhist<<<PNB, 256, 0, stream>>>(dst, ghist, cnt, ZN);
    bscan<<<1, 256, 0, stream>>>(ghist, gcursor, batch, cntg, ybfA, ybfB);
    bpart<<<PNB, 256, 0, stream>>>(src, dst, gcursor, epart);
    fillp<<<PNB, 256, 0, stream>>>(epart, cnt, col);
    pad_rows<<<(N_NODES + 255) / 256, 256, 0, stream>>>(cnt, col);

    // ---- weight transposes + layer-0 pre-projection ----
    wtrans<<<8, 256, 0, stream>>>(W1f, W2f, W1r, W2r, W1fT, WT2, WTn);
    proj0<<<N_NODES / 16, 256, 0, stream>>>(x, W1fT, ybfA);

    // ---- 4 fused layers ----
    const int NB = N_NODES / 4;                                 // 25000
    const long PL = (long)NREP * NUM_GRAPHS * HID;
    layer_fused<true><<<NB, 256, 0, stream>>>(
        ybfA, cnt, col, batch, b1f, WT2, b2f,
        WTn, ybfB, pooled);
    layer_fused<true><<<NB, 256, 0, stream>>>(
        ybfB, cnt, col, batch, b1r, WT2 + 4096, b2r,
        WTn + 4096, ybfA, pooled + 1 * PL);
    layer_fused<true><<<NB, 256, 0, stream>>>(
        ybfA, cnt, col, batch, b1r + HID, WT2 + 2 * 4096, b2r + HID,
        WTn + 2 * 4096, ybfB, pooled + 2 * PL);
    layer_fused<false><<<NB, 256, 0, stream>>>(
        ybfB, cnt, col, batch, b1r + 2 * HID, WT2 + 3 * 4096, b2r + 2 * HID,
        nullptr, nullptr, pooled + 3 * PL);

    // ---- JK on pooled sums + classifier ----
    jk_pool<<<NUM_GRAPHS, 64, 0, stream>>>(pooled, cntg, Wjk, bjk, pooled_jk);
    cls_all<<<1, 256, 0, stream>>>(pooled_jk, Wc1, bc1, gamma, beta, Wc2, bc2,
                                   (float*)d_out);
}

// Round 14
// 725.322 us; speedup vs baseline: 2.2879x; 2.2879x over previous
//
#include <hip/hip_runtime.h>
#include <hip/hip_bf16.h>

#define N_NODES    100000
#define N_EDGES    1600000
#define IN_CH      128
#define HID        64
#define N_LAYERS   4
#define OUT_CH     10
#define NUM_GRAPHS 128
#define BN_EPS     1e-5f
#define CAP        64             // padded CSR row capacity (max deg ~36 at Poisson(16))
#define NREP       8              // pooled replicas (cuts per-address atomic chains 8x)
#define NBKT       256            // dst>>9 -> buckets 0..195 (256 slots for pow2 LDS)
#define EPB        2048           // edges per block in partition kernels
#define PNB        782            // ceil(1.6M / 2048)
#define PADM       24             // row pad multiple: 12 dual-loads per batch

typedef __hip_bfloat16 bf16;
typedef unsigned int uint32;

__device__ __forceinline__ float bf2f(bf16 v) { return __bfloat162float(v); }
// unpack packed bf16x2 dword -> float2 (bf16 -> f32 is <<16)
__device__ __forceinline__ float2 unpk(uint32 p) {
    float2 r;
    r.x = __uint_as_float(p << 16);
    r.y = __uint_as_float(p & 0xffff0000u);
    return r;
}

// ---------------- tiny zero (ghist only; cnt/pooled zeroed inside bhist) -----
__global__ void zero_i(int* __restrict__ p, int n) {
    int i = threadIdx.x;
    for (; i < n; i += 256) p[i] = 0;
}

// ---------------- bucket histogram (LDS-aggregated) + bulk zeroing -----------
__global__ void bhist(const int* __restrict__ dst, int* __restrict__ ghist,
                      int* __restrict__ zbase, int zn) {
    __shared__ int h[NBKT];
    int t = threadIdx.x;
    h[t] = 0;
    // fused zeroing of cnt+pooled (disjoint from this kernel's own arrays)
    for (int i = blockIdx.x * 256 + t; i < zn; i += gridDim.x * 256) zbase[i] = 0;
    __syncthreads();
    long base = (long)blockIdx.x * EPB;
    for (int u = 0; u < 8; u++) {
        long e = base + u * 256 + t;
        if (e < N_EDGES) atomicAdd(&h[dst[e] >> 9], 1);
    }
    __syncthreads();
    if (h[t]) atomicAdd(&ghist[t], h[t]);
}

// ---------------- bucket scan + cntg (binary search) + ybf pad-row zero ------
__global__ void bscan(const int* __restrict__ ghist, int* __restrict__ gcursor,
                      const int* __restrict__ batch, int* __restrict__ cntg,
                      bf16* __restrict__ ybfA, bf16* __restrict__ ybfB) {
    __shared__ int sh[NBKT];
    int t = threadIdx.x;                          // 256 threads
    int v = ghist[t];
    sh[t] = v;
    __syncthreads();
    for (int off = 1; off < NBKT; off <<= 1) {
        int a = (t >= off) ? sh[t - off] : 0;
        __syncthreads();
        sh[t] += a;
        __syncthreads();
    }
    gcursor[t] = sh[t] - v;                       // exclusive bucket base
    if (t < NUM_GRAPHS) {                         // per-graph node counts
        int g = t, lo = 0, hi = N_NODES;
        while (lo < hi) { int m = (lo + hi) >> 1; if (batch[m] < g) lo = m + 1; else hi = m; }
        int lb = lo;
        lo = 0; hi = N_NODES;
        while (lo < hi) { int m = (lo + hi) >> 1; if (batch[m] < g + 1) lo = m + 1; else hi = m; }
        cntg[g] = lo - lb;
    }
    if (t < HID) {                                // sentinel zero-row for tail-free gather
        ybfA[(long)N_NODES * HID + t] = __float2bfloat16(0.f);
        ybfB[(long)N_NODES * HID + t] = __float2bfloat16(0.f);
    }
}

// ---------------- partition edges into bucket order --------------------------
__global__ void bpart(const int* __restrict__ src, const int* __restrict__ dst,
                      int* __restrict__ gcursor, int2* __restrict__ epart) {
    __shared__ int h[NBKT];
    __shared__ int cur[NBKT];
    int t = threadIdx.x;
    h[t] = 0;
    __syncthreads();
    long base = (long)blockIdx.x * EPB;
    int myd[8], mys[8];
    for (int u = 0; u < 8; u++) {
        long e = base + u * 256 + t;
        if (e < N_EDGES) {
            myd[u] = dst[e];
            mys[u] = src[e];
            atomicAdd(&h[myd[u] >> 9], 1);
        } else myd[u] = -1;
    }
    __syncthreads();
    if (h[t]) cur[t] = atomicAdd(&gcursor[t], h[t]);
    __syncthreads();
    for (int u = 0; u < 8; u++) {
        if (myd[u] >= 0) {
            int pos = atomicAdd(&cur[myd[u] >> 9], 1);
            epart[pos] = make_int2(mys[u], myd[u]);
        }
    }
}

// ---------------- fill padded CSR from bucket-sorted edges -------------------
__global__ void fillp(const int2* __restrict__ epart, int* __restrict__ cnt,
                      int* __restrict__ col) {
    int t = threadIdx.x;
    long base = (long)blockIdx.x * EPB;
    for (int u = 0; u < 8; u++) {
        long e = base + u * 256 + t;
        if (e < N_EDGES) {
            int2 p = epart[e];
            int slot = atomicAdd(&cnt[p.y], 1);
            col[p.y * CAP + slot] = p.x;
        }
    }
}

// ---------------- layer-0 pre-projection + row padding (fused) ---------------
// 4 nodes per wave; W1 row-major coalesced scalar loads (R12-proven).
// Also pads this block's 16 rows of col to a multiple of PADM with sentinel.
__global__ void proj0(const float* __restrict__ x, const float* __restrict__ W1,
                      bf16* __restrict__ ybf, const int* __restrict__ cnt,
                      int* __restrict__ col) {
    __shared__ float xsh[4][4][IN_CH];            // 8 KB
    const int wave = threadIdx.x >> 6, lane = threadIdx.x & 63;
    const int nb = blockIdx.x * 16 + wave * 4;    // 6250 * 16 == 100000

    // ---- fused pad_rows for this block's 16 nodes (16 threads per node) ----
    {
        int r = threadIdx.x >> 4, j = threadIdx.x & 15;
        int pn = blockIdx.x * 16 + r;
        int c = cnt[pn];
        int cp = ((c + PADM - 1) / PADM) * PADM;  // <= 48 for max deg ~36
        int s0 = c + j, s1 = c + 16 + j;
        if (s0 < cp) col[pn * CAP + s0] = N_NODES;
        if (s1 < cp) col[pn * CAP + s1] = N_NODES;
    }

    #pragma unroll
    for (int r = 0; r < 4; r++) {
        float2 v = ((const float2*)(x + (long)(nb + r) * IN_CH))[lane];
        xsh[wave][r][2 * lane]     = v.x;         // 2-way bank alias: free
        xsh[wave][r][2 * lane + 1] = v.y;
    }
    // per-wave LDS slice: wave-lockstep + compiler lgkmcnt; no barrier
    float a0 = 0.f, a1 = 0.f, a2 = 0.f, a3 = 0.f;
    for (int k = 0; k < IN_CH; k += 4) {
        float4 q0 = *(const float4*)&xsh[wave][0][k];
        float4 q1 = *(const float4*)&xsh[wave][1][k];
        float4 q2 = *(const float4*)&xsh[wave][2][k];
        float4 q3 = *(const float4*)&xsh[wave][3][k];
        float w0 = W1[(k + 0) * 64 + lane];
        float w1 = W1[(k + 1) * 64 + lane];
        float w2 = W1[(k + 2) * 64 + lane];
        float w3 = W1[(k + 3) * 64 + lane];
        a0 += q0.x * w0 + q0.y * w1 + q0.z * w2 + q0.w * w3;
        a1 += q1.x * w0 + q1.y * w1 + q1.z * w2 + q1.w * w3;
        a2 += q2.x * w0 + q2.y * w1 + q2.z * w2 + q2.w * w3;
        a3 += q3.x * w0 + q3.y * w1 + q3.z * w2 + q3.w * w3;
    }
    ybf[(long)(nb + 0) * 64 + lane] = __float2bfloat16(a0);
    ybf[(long)(nb + 1) * 64 + lane] = __float2bfloat16(a1);
    ybf[(long)(nb + 2) * 64 + lane] = __float2bfloat16(a2);
    ybf[(long)(nb + 3) * 64 + lane] = __float2bfloat16(a3);
}

// ---------------- fused layer: dual-row gather -> relu -> W2 -> pool (+W1n) --
// 12-deep dual batches (24 slots); row-major coalesced weight loads (R12).
template <bool HAS_NEXT>
__global__ void layer_fused(const bf16* __restrict__ ybf, const int* __restrict__ cnt,
                            const int* __restrict__ col, const int* __restrict__ batch,
                            const float* __restrict__ b1, const float* __restrict__ W2,
                            const float* __restrict__ b2, const float* __restrict__ W1n,
                            bf16* __restrict__ ynext, float* __restrict__ pooled_l) {
    __shared__ float csh[4][2][2 * HID];          // half-sums, 4 KB
    __shared__ float tsh[4][64];
    __shared__ float hsh[4][64];
    const int wave = threadIdx.x >> 6, lane = threadIdx.x & 63;
    const int hl = lane & 31;
    const bool hi = lane >= 32;
    const int nA = blockIdx.x * 4;
    const int n = __builtin_amdgcn_readfirstlane(nA + wave);
    const int degc = __builtin_amdgcn_readfirstlane(cnt[n]);
    const int degp = ((degc + PADM - 1) / PADM) * PADM;
    const int g = __builtin_amdgcn_readfirstlane(batch[n]);
    const long s = (long)n * CAP;
    const uint32* yrow = (const uint32*)ybf;

    float2 a0 = {0.f, 0.f}, a1 = {0.f, 0.f}, a2 = {0.f, 0.f}, a3 = {0.f, 0.f};
    for (int i = 0; i < degp; i += PADM) {
        uint32 p[12];
        #pragma unroll
        for (int u = 0; u < 12; u++) {
            int c0 = __builtin_amdgcn_readfirstlane(col[s + i + 2 * u]);
            int c1 = __builtin_amdgcn_readfirstlane(col[s + i + 2 * u + 1]);
            int c = hi ? c1 : c0;
            p[u] = yrow[(long)c * 32 + hl];
        }
        #pragma unroll
        for (int u = 0; u < 12; u++) {
            float2 f = unpk(p[u]);
            if ((u & 3) == 0) { a0.x += f.x; a0.y += f.y; }
            else if ((u & 3) == 1) { a1.x += f.x; a1.y += f.y; }
            else if ((u & 3) == 2) { a2.x += f.x; a2.y += f.y; }
            else { a3.x += f.x; a3.y += f.y; }
        }
    }
    float2 hs;
    hs.x = (a0.x + a1.x) + (a2.x + a3.x);
    hs.y = (a0.y + a1.y) + (a2.y + a3.y);
    ((float2*)&csh[wave][hi ? 1 : 0][0])[hl] = hs;   // channels (2hl, 2hl+1)
    // per-wave slice: lockstep + compiler lgkmcnt; no barrier
    float t = bf2f(ybf[(long)n * 64 + lane]) + b1[lane]
            + csh[wave][0][lane] + csh[wave][1][lane];
    t = fmaxf(t, 0.f);
    tsh[wave][lane] = t;

    float h = b2[lane];
    for (int k = 0; k < 64; k += 4) {
        float4 tv = *(const float4*)&tsh[wave][k];
        h += tv.x * W2[(k + 0) * 64 + lane];
        h += tv.y * W2[(k + 1) * 64 + lane];
        h += tv.z * W2[(k + 2) * 64 + lane];
        h += tv.w * W2[(k + 3) * 64 + lane];
    }
    h = fmaxf(h, 0.f);
    hsh[wave][lane] = h;

    if (HAS_NEXT) {               // reads only own wave's hsh slice: pre-barrier OK
        float yn = 0.f;
        for (int k = 0; k < 64; k += 4) {
            float4 hv = *(const float4*)&hsh[wave][k];
            yn += hv.x * W1n[(k + 0) * 64 + lane];
            yn += hv.y * W1n[(k + 1) * 64 + lane];
            yn += hv.z * W1n[(k + 2) * 64 + lane];
            yn += hv.w * W1n[(k + 3) * 64 + lane];
        }
        ynext[(long)n * 64 + lane] = __float2bfloat16(yn);
    }

    // block-aggregated pool contribution (replicated target cuts chains 8x)
    __syncthreads();
    float* rep = pooled_l + (long)(blockIdx.x & (NREP - 1)) * NUM_GRAPHS * HID;
    const int gA = __builtin_amdgcn_readfirstlane(batch[nA]);
    const int gD = __builtin_amdgcn_readfirstlane(batch[nA + 3]);
    if (gA == gD) {               // 99.5% of blocks: whole block same graph
        if (wave == 0) {
            float sum = (hsh[0][lane] + hsh[1][lane]) + (hsh[2][lane] + hsh[3][lane]);
            atomicAdd(&rep[gA * 64 + lane], sum);
        }
    } else {
        atomicAdd(&rep[g * 64 + lane], h);
    }
}

// ---------------- JK projection on pooled sums (exact: pooling is linear) ----
__global__ void jk_pool(const float* __restrict__ pooled, const int* __restrict__ cntg,
                        const float* __restrict__ Wjk, const float* __restrict__ bjk,
                        float* __restrict__ pooled_jk) {
    __shared__ float sh[64];
    int g = blockIdx.x, j = threadIdx.x;          // 128 blocks x 64 threads (1 wave)
    float acc = (float)cntg[g] * bjk[j];
    for (int l = 0; l < N_LAYERS; l++) {
        float s = 0.f;
        for (int r = 0; r < NREP; r++)
            s += pooled[((long)(l * NREP + r) * NUM_GRAPHS + g) * 64 + j];
        sh[j] = s;                                // single wave: lockstep, no barrier
        const float* W = Wjk + (long)l * HID * 64;
        for (int k = 0; k < 64; k++) acc += sh[k] * W[k * 64 + j];
    }
    pooled_jk[g * 64 + j] = acc;
}

// ---------------- classifier: Linear -> BN(batch stats) -> ReLU -> Linear ----
__global__ void cls_all(const float* __restrict__ pooled_jk,
                        const float* __restrict__ Wc1, const float* __restrict__ bc1,
                        const float* __restrict__ gamma, const float* __restrict__ beta,
                        const float* __restrict__ Wc2, const float* __restrict__ bc2,
                        float* __restrict__ out) {
    __shared__ float Z[NUM_GRAPHS * HID];         // 32 KB
    __shared__ float mu[HID], rs[HID];
    int tid = threadIdx.x;                        // 256

    for (int i = tid; i < NUM_GRAPHS * HID; i += 256) {
        int g = i >> 6, j = i & 63;
        float acc = bc1[j];
        for (int k = 0; k < 64; k++) acc += pooled_jk[g * 64 + k] * Wc1[k * 64 + j];
        Z[i] = acc;
    }
    __syncthreads();
    if (tid < HID) {
        float s = 0.f, sq = 0.f;
        for (int g = 0; g < NUM_GRAPHS; g++) {
            float v = Z[g * 64 + tid];
            s += v; sq += v * v;
        }
        float m = s / NUM_GRAPHS;
        mu[tid] = m;
        rs[tid] = rsqrtf(sq / NUM_GRAPHS - m * m + BN_EPS);
    }
    __syncthreads();
    for (int i = tid; i < NUM_GRAPHS * OUT_CH; i += 256) {
        int g = i / OUT_CH, o = i % OUT_CH;
        float acc = bc2[o];
        for (int j = 0; j < 64; j++) {
            float v = (Z[g * 64 + j] - mu[j]) * rs[j] * gamma[j] + beta[j];
            acc += fmaxf(v, 0.f) * Wc2[j * OUT_CH + o];
        }
        out[i] = acc;
    }
}

// -----------------------------------------------------------------------------
extern "C" void kernel_launch(void* const* d_in, const int* in_sizes, int n_in,
                              void* d_out, int out_size, void* d_ws, size_t ws_size,
                              hipStream_t stream) {
    const float* x     = (const float*)d_in[0];
    const int*   ei    = (const int*)d_in[1];
    const int*   batch = (const int*)d_in[2];
    const float* W1f   = (const float*)d_in[3];
    const float* b1f   = (const float*)d_in[4];
    const float* W2f   = (const float*)d_in[5];
    const float* b2f   = (const float*)d_in[6];
    const float* W1r   = (const float*)d_in[7];
    const float* b1r   = (const float*)d_in[8];
    const float* W2r   = (const float*)d_in[9];
    const float* b2r   = (const float*)d_in[10];
    const float* Wjk   = (const float*)d_in[11];
    const float* bjk   = (const float*)d_in[12];
    const float* Wc1   = (const float*)d_in[13];
    const float* bc1   = (const float*)d_in[14];
    const float* gamma = (const float*)d_in[15];
    const float* beta  = (const float*)d_in[16];
    const float* Wc2   = (const float*)d_in[17];
    const float* bc2   = (const float*)d_in[18];

    const int* src = ei;
    const int* dst = ei + N_EDGES;

    // workspace layout (all segments 16-B aligned)
    float* ws        = (float*)d_ws;
    float* pooled_jk = ws;                                      // 8192 floats
    bf16*  ybfA      = (bf16*)(pooled_jk + NUM_GRAPHS * HID);   // (N+1)*64 bf16
    bf16*  ybfB      = ybfA + (long)(N_NODES + 1) * HID;        // (N+1)*64 bf16
    int*   cnt       = (int*)(ybfB + (long)(N_NODES + 1) * HID);// 100000
    float* pooled    = (float*)(cnt + N_NODES);                 // 262144 floats
    int*   ghist     = (int*)(pooled + (long)N_LAYERS * NREP * NUM_GRAPHS * HID); // 256
    int*   gcursor   = ghist + NBKT;                            // 256
    int*   cntg      = gcursor + NBKT;                          // 128 (+pad 128)
    int*   col       = cntg + 256;                              // 6.4M ints
    int2*  epart     = (int2*)(col + (long)N_NODES * CAP);      // 1.6M int2
    const int ZN = N_NODES + N_LAYERS * NREP * NUM_GRAPHS * HID; // cnt + pooled

    // ---- CSR build: zero(ghist) -> hist(+bulk zero) -> scan -> part -> fill --
    zero_i<<<1, 256, 0, stream>>>(ghist, NBKT);
    bhist<<<PNB, 256, 0, stream>>>(dst, ghist, cnt, ZN);
    bscan<<<1, 256, 0, stream>>>(ghist, gcursor, batch, cntg, ybfA, ybfB);
    bpart<<<PNB, 256, 0, stream>>>(src, dst, gcursor, epart);
    fillp<<<PNB, 256, 0, stream>>>(epart, cnt, col);

    // ---- layer-0 pre-projection (+ fused row padding) ----
    proj0<<<N_NODES / 16, 256, 0, stream>>>(x, W1f, ybfA, cnt, col);

    // ---- 4 fused layers ----
    const int NB = N_NODES / 4;                                 // 25000
    const long PL = (long)NREP * NUM_GRAPHS * HID;
    layer_fused<true><<<NB, 256, 0, stream>>>(
        ybfA, cnt, col, batch, b1f, W2f, b2f,
        W1r, ybfB, pooled);
    layer_fused<true><<<NB, 256, 0, stream>>>(
        ybfB, cnt, col, batch, b1r, W2r, b2r,
        W1r + (long)1 * HID * HID, ybfA, pooled + 1 * PL);
    layer_fused<true><<<NB, 256, 0, stream>>>(
        ybfA, cnt, col, batch, b1r + HID, W2r + (long)1 * HID * HID, b2r + HID,
        W1r + (long)2 * HID * HID, ybfB, pooled + 2 * PL);
    layer_fused<false><<<NB, 256, 0, stream>>>(
        ybfB, cnt, col, batch, b1r + 2 * HID, W2r + (long)2 * HID * HID, b2r + 2 * HID,
        nullptr, nullptr, pooled + 3 * PL);

    // ---- JK on pooled sums + classifier ----
    jk_pool<<<NUM_GRAPHS, 64, 0, stream>>>(pooled, cntg, Wjk, bjk, pooled_jk);
    cls_all<<<1, 256, 0, stream>>>(pooled_jk, Wc1, bc1, gamma, beta, Wc2, bc2,
                                   (float*)d_out);
}